// Round 1
// baseline (469.670 us; speedup 1.0000x reference)
//
#include <hip/hip_runtime.h>
#include <math.h>

// Problem constants (fixed by setup_inputs)
#define NWORDS 8192
#define LW     24
#define VOC    128
#define DIM    512
#define NH     8
#define DKH    64
#define GNAMES 2048
#define F2     256

// ---------------- generic tiled fp32 SGEMM: C = act(A[M,K] @ B[K,N]) -----------
// 64x64 block tile, BK=16, 16x16 threads, 4x4 per-thread register tile.
// All M,N,K here are multiples of 64/16 -> no bounds checks.
template<int ACT>
__global__ __launch_bounds__(256) void k_sgemm(const float* __restrict__ A,
                                               const float* __restrict__ B,
                                               float* __restrict__ C,
                                               int M, int N, int K) {
  __shared__ float As[16][65];  // As[k][m], +1 pad to avoid bank conflicts
  __shared__ float Bs[16][65];  // Bs[k][n]
  const int t  = threadIdx.x;
  const int tx = t & 15, ty = t >> 4;
  const int m0 = blockIdx.y * 64, n0 = blockIdx.x * 64;
  float acc[4][4] = {};
  for (int k0 = 0; k0 < K; k0 += 16) {
    #pragma unroll
    for (int i = 0; i < 4; ++i) {
      int idx = t + 256 * i;          // 0..1023 covering 64x16
      int m = idx >> 4, k = idx & 15; // A tile
      As[k][m] = A[(size_t)(m0 + m) * K + k0 + k];
    }
    #pragma unroll
    for (int i = 0; i < 4; ++i) {
      int idx = t + 256 * i;          // 0..1023 covering 16x64
      int kk = idx >> 6, nn = idx & 63;
      Bs[kk][nn] = B[(size_t)(k0 + kk) * N + n0 + nn];
    }
    __syncthreads();
    #pragma unroll
    for (int k = 0; k < 16; ++k) {
      float a[4], b[4];
      #pragma unroll
      for (int i = 0; i < 4; ++i) a[i] = As[k][ty * 4 + i];
      #pragma unroll
      for (int j = 0; j < 4; ++j) b[j] = Bs[k][tx * 4 + j];
      #pragma unroll
      for (int i = 0; i < 4; ++i)
        #pragma unroll
        for (int j = 0; j < 4; ++j)
          acc[i][j] += a[i] * b[j];
    }
    __syncthreads();
  }
  #pragma unroll
  for (int i = 0; i < 4; ++i)
    #pragma unroll
    for (int j = 0; j < 4; ++j) {
      float v = acc[i][j];
      if (ACT == 1) v = tanhf(v);
      C[(size_t)(m0 + ty * 4 + i) * N + n0 + tx * 4 + j] = v;
    }
}

// ---------------- qk score table: tab[h][c1][c2] = (EQ[c1,h*64:] . EK[c2,h*64:]) / 8
__global__ __launch_bounds__(128) void k_qk_tab(const float* __restrict__ EQ,
                                                const float* __restrict__ EK,
                                                float* __restrict__ tab) {
  const int c1 = blockIdx.x, h = blockIdx.y, c2 = threadIdx.x;
  __shared__ float qrow[DKH];
  if (threadIdx.x < DKH) qrow[threadIdx.x] = EQ[c1 * DIM + h * DKH + threadIdx.x];
  __syncthreads();
  const float* krow = EK + c2 * DIM + h * DKH;
  float acc = 0.f;
  #pragma unroll
  for (int d = 0; d < DKH; ++d) acc += qrow[d] * krow[d];
  tab[(h * VOC + c1) * VOC + c2] = acc * 0.125f;  // scale = 1/sqrt(64)
}

// ---------------- per-word attention -> char-mean-pooled output [NWORDS, DIM]
// block = 192 threads = (8 heads x 24 query positions)
__global__ __launch_bounds__(192) void k_attn(const int* __restrict__ inputs,
                                              const float* __restrict__ tab,
                                              const float* __restrict__ EV,
                                              float* __restrict__ word_pooled) {
  const int n = blockIdx.x;
  const int t = threadIdx.x;
  __shared__ int   cs[LW];
  __shared__ float att[NH][LW][LW];  // normalized attn, zero rows for pad queries
  __shared__ float w[NH][LW];        // sum over (non-pad) queries

  if (t < LW) cs[t] = inputs[n * LW + t];
  __syncthreads();

  // phase 1: per-(head, qp) softmax row
  const int h = t / LW, qp = t % LW;
  const int cq = cs[qp];
  float row[LW];
  if (cq != 0) {
    const float* trow = tab + (h * VOC + cq) * VOC;
    float mx = -1e30f;
    #pragma unroll
    for (int kp = 0; kp < LW; ++kp) {
      int ck = cs[kp];
      float s = (ck != 0) ? trow[ck] : -1e30f;
      row[kp] = s;
      mx = fmaxf(mx, s);
    }
    float sum = 0.f;
    #pragma unroll
    for (int kp = 0; kp < LW; ++kp) {
      float e = (row[kp] > -1e29f) ? __expf(row[kp] - mx) : 0.f;
      row[kp] = e;
      sum += e;
    }
    float inv = 1.f / sum;
    #pragma unroll
    for (int kp = 0; kp < LW; ++kp) att[h][qp][kp] = row[kp] * inv;
  } else {
    #pragma unroll
    for (int kp = 0; kp < LW; ++kp) att[h][qp][kp] = 0.f;
  }
  __syncthreads();

  // phase 2: w[h][kp] = sum_qp att[h][qp][kp]  (pad-q rows are zero already)
  {
    const int hh = t / LW, kp = t % LW;
    float acc = 0.f;
    #pragma unroll
    for (int q = 0; q < LW; ++q) acc += att[hh][q][kp];
    w[hh][kp] = acc;
  }
  __syncthreads();

  // phase 3: pooled[j] = (1/cnt) * sum_kp w[h(j)][kp] * EV[c_kp][j]
  int cnt = 0;
  #pragma unroll
  for (int l = 0; l < LW; ++l) cnt += (cs[l] != 0);
  const float invc = cnt ? 1.f / (float)cnt : 0.f;
  for (int j = t; j < DIM; j += 192) {
    const int hh = j >> 6;
    float acc = 0.f;
    #pragma unroll
    for (int kp = 0; kp < LW; ++kp) {
      int ck = cs[kp];
      if (ck != 0) acc += w[hh][kp] * EV[ck * DIM + j];
    }
    word_pooled[(size_t)n * DIM + j] = acc * invc;
  }
}

// ---------------- exclusive scan of n_words (2048 = 256*8) ----------------
__global__ __launch_bounds__(256) void k_scan(const int* __restrict__ nw, int* __restrict__ offs) {
  __shared__ int part[256];
  const int t = threadIdx.x;
  int v[8];
  int s = 0;
  #pragma unroll
  for (int i = 0; i < 8; ++i) { v[i] = nw[t * 8 + i]; s += v[i]; }
  part[t] = s;
  __syncthreads();
  if (t == 0) {
    int a = 0;
    for (int i = 0; i < 256; ++i) { int x = part[i]; part[i] = a; a += x; }
    offs[GNAMES] = a;
  }
  __syncthreads();
  int a = part[t];
  #pragma unroll
  for (int i = 0; i < 8; ++i) { offs[t * 8 + i] = a; a += v[i]; }
}

// ---------------- name-level mean over word groups ----------------
__global__ __launch_bounds__(256) void k_name_pool(const float* __restrict__ wp,
                                                   const int* __restrict__ offs,
                                                   float* __restrict__ np_) {
  const int idx = blockIdx.x * 256 + threadIdx.x;  // < GNAMES*DIM
  const int g = idx >> 9, d = idx & 511;
  const int o0 = offs[g], o1 = offs[g + 1];
  float acc = 0.f;
  for (int wi = o0; wi < o1; ++wi) acc += wp[(size_t)wi * DIM + d];
  np_[idx] = (o1 > o0) ? acc / (float)(o1 - o0) : 0.f;
}

extern "C" void kernel_launch(void* const* d_in, const int* in_sizes, int n_in,
                              void* d_out, int out_size, void* d_ws, size_t ws_size,
                              hipStream_t stream) {
  const int*   inputs  = (const int*)d_in[0];
  const int*   n_words = (const int*)d_in[1];
  const float* emb     = (const float*)d_in[3];
  const float* Wq      = (const float*)d_in[4];
  const float* Wk      = (const float*)d_in[5];
  const float* Wv      = (const float*)d_in[6];
  const float* Wo      = (const float*)d_in[7];
  const float* W1      = (const float*)d_in[8];
  const float* W2      = (const float*)d_in[9];
  float* out = (float*)d_out;

  // workspace layout (floats)
  float* ws  = (float*)d_ws;
  float* EQ  = ws;                   // 128*512      = 65536
  float* EK  = ws + 65536;           // 128*512
  float* EV  = ws + 131072;          // 128*512
  float* TAB = ws + 196608;          // 8*128*128    = 131072
  float* WF  = ws + 327680;          // 512*512      = 262144
  float* WP  = ws + 589824;          // 8192*512     = 4194304
  float* NP  = ws + 4784128;         // 2048*512     = 1048576
  float* H1  = ws + 5832704;         // 2048*512     = 1048576
  int*   OFFS = (int*)(ws + 6881280); // 2049 ints   (total ~26.3 MiB)

  // EQ/EK/EV = emb @ W{q,k,v}   (M=128, N=512, K=512)
  k_sgemm<0><<<dim3(8, 2), 256, 0, stream>>>(emb, Wq, EQ, 128, 512, 512);
  k_sgemm<0><<<dim3(8, 2), 256, 0, stream>>>(emb, Wk, EK, 128, 512, 512);
  k_sgemm<0><<<dim3(8, 2), 256, 0, stream>>>(emb, Wv, EV, 128, 512, 512);
  // Wfused = Wo @ W1 (512x512x512)
  k_sgemm<0><<<dim3(8, 8), 256, 0, stream>>>(Wo, W1, WF, 512, 512, 512);
  // qk score table
  k_qk_tab<<<dim3(VOC, NH), 128, 0, stream>>>(EQ, EK, TAB);
  // word-group offsets
  k_scan<<<1, 256, 0, stream>>>(n_words, OFFS);
  // attention + char-mean pooling per word
  k_attn<<<NWORDS, 192, 0, stream>>>(inputs, TAB, EV, WP);
  // name-level mean pooling
  k_name_pool<<<(GNAMES * DIM) / 256, 256, 0, stream>>>(WP, OFFS, NP);
  // h1 = tanh(NP @ WF)   (2048x512x512)
  k_sgemm<1><<<dim3(8, 32), 256, 0, stream>>>(NP, WF, H1, 2048, 512, 512);
  // out = tanh(h1 @ W2)  (2048x256x512)
  k_sgemm<1><<<dim3(4, 32), 256, 0, stream>>>(H1, W2, out, 2048, F2, 512);
}

// Round 2
// 238.321 us; speedup vs baseline: 1.9707x; 1.9707x over previous
//
#include <hip/hip_runtime.h>
#include <math.h>

// Problem constants (fixed by setup_inputs)
#define NWORDS 8192
#define LW     24
#define VOC    128
#define DIM    512
#define NH     8
#define DKH    64
#define GNAMES 2048
#define F2     256

// ---------------- generic tiled fp32 SGEMM: C = act(A[M,K] @ B[K,N]) -----------
// 64x64 block tile, BK=16, 16x16 threads, 4x4 per-thread register tile.
template<int ACT>
__global__ __launch_bounds__(256) void k_sgemm(const float* __restrict__ A,
                                               const float* __restrict__ B,
                                               float* __restrict__ C,
                                               int M, int N, int K) {
  __shared__ float As[16][68];  // pad 68 -> row stride 272B (16B aligned), 2-way bank alias only
  __shared__ float Bs[16][68];
  const int t  = threadIdx.x;
  const int tx = t & 15, ty = t >> 4;
  const int m0 = blockIdx.y * 64, n0 = blockIdx.x * 64;
  float acc[4][4] = {};
  for (int k0 = 0; k0 < K; k0 += 16) {
    #pragma unroll
    for (int i = 0; i < 4; ++i) {
      int idx = t + 256 * i;          // 0..1023 covering 64x16
      int m = idx >> 4, k = idx & 15; // A tile
      As[k][m] = A[(size_t)(m0 + m) * K + k0 + k];
    }
    #pragma unroll
    for (int i = 0; i < 4; ++i) {
      int idx = t + 256 * i;          // 0..1023 covering 16x64
      int kk = idx >> 6, nn = idx & 63;
      Bs[kk][nn] = B[(size_t)(k0 + kk) * N + n0 + nn];
    }
    __syncthreads();
    #pragma unroll
    for (int k = 0; k < 16; ++k) {
      float a[4], b[4];
      #pragma unroll
      for (int i = 0; i < 4; ++i) a[i] = As[k][ty * 4 + i];
      #pragma unroll
      for (int j = 0; j < 4; ++j) b[j] = Bs[k][tx * 4 + j];
      #pragma unroll
      for (int i = 0; i < 4; ++i)
        #pragma unroll
        for (int j = 0; j < 4; ++j)
          acc[i][j] += a[i] * b[j];
    }
    __syncthreads();
  }
  #pragma unroll
  for (int i = 0; i < 4; ++i)
    #pragma unroll
    for (int j = 0; j < 4; ++j) {
      float v = acc[i][j];
      if (ACT == 1) v = tanhf(v);
      C[(size_t)(m0 + ty * 4 + i) * N + n0 + tx * 4 + j] = v;
    }
}

// ---------------- exp(qk) table: ETAB[c1][c2][h] = exp((EQ[c1,h*64:] . EK[c2,h*64:]) / 8)
// h innermost so the 8 h-lanes of a q-group gather 32B contiguous.
__global__ __launch_bounds__(128) void k_qk_tab(const float* __restrict__ EQ,
                                                const float* __restrict__ EK,
                                                float* __restrict__ etab) {
  const int c1 = blockIdx.x, h = blockIdx.y, c2 = threadIdx.x;
  __shared__ float qrow[DKH];
  if (threadIdx.x < DKH) qrow[threadIdx.x] = EQ[c1 * DIM + h * DKH + threadIdx.x];
  __syncthreads();
  const float* krow = EK + c2 * DIM + h * DKH;
  float acc = 0.f;
  #pragma unroll
  for (int d = 0; d < DKH; ++d) acc += qrow[d] * krow[d];
  etab[(c1 * VOC + c2) * NH + h] = __expf(acc * 0.125f);  // scale = 1/sqrt(64)
}

// ---------------- per-word attention -> char-mean-pooled output [NWORDS, DIM]
// block = 192 threads = 24 query positions x 8 heads, t = q*8 + h (h fastest
// so table gathers coalesce into 32B segments per q-group).
__global__ __launch_bounds__(192) void k_attn(const int* __restrict__ inputs,
                                              const float* __restrict__ etab,
                                              const float* __restrict__ EV,
                                              float* __restrict__ word_pooled) {
  const int n = blockIdx.x;
  const int t = threadIdx.x;
  __shared__ int   cs[LW];
  __shared__ float sc[LW * NH * 25];  // sc[(q*8+h)*25 + kp]; 25 odd -> conflict-free
  __shared__ float w[NH * LW];        // w[h*24+kp] = sum over q of normalized rows

  if (t < LW) cs[t] = inputs[n * LW + t];
  __syncthreads();

  // phase 1: per-(q,h) softmax row (exp pre-baked in table; no max pass needed,
  // scores are ~|0.01| so exp is well-conditioned)
  {
    const int q = t >> 3, h = t & 7;
    const int cq = cs[q];
    if (cq != 0) {
      const float* tb = etab + cq * (VOC * NH) + h;
      float row[LW];
      float sum = 0.f;
      #pragma unroll
      for (int kp = 0; kp < LW; ++kp) {
        int ck = cs[kp];
        float e = (ck != 0) ? tb[ck * NH] : 0.f;
        row[kp] = e;
        sum += e;
      }
      float inv = 1.f / sum;
      #pragma unroll
      for (int kp = 0; kp < LW; ++kp) sc[t * 25 + kp] = row[kp] * inv;
    } else {
      #pragma unroll
      for (int kp = 0; kp < LW; ++kp) sc[t * 25 + kp] = 0.f;
    }
  }
  __syncthreads();

  // phase 2: w[h][kp] = sum_q sc[q][h][kp]  (consecutive kp lanes -> conflict-free)
  {
    const int hh = t / 24, kp = t % 24;
    float acc = 0.f;
    #pragma unroll
    for (int q = 0; q < LW; ++q) acc += sc[(q * 8 + hh) * 25 + kp];
    w[hh * LW + kp] = acc;
  }
  __syncthreads();

  // phase 3: pooled[j] = (1/cnt) * sum_kp w[h(j)][kp] * EV[c_kp][j], float4 over j
  int cnt = 0;
  #pragma unroll
  for (int l = 0; l < LW; ++l) cnt += (cs[l] != 0);
  const float invc = cnt ? 1.f / (float)cnt : 0.f;
  if (t < 128) {
    const int hh = t >> 4;  // (t*4)>>6
    const float4* EV4 = (const float4*)EV;
    float4 acc = make_float4(0.f, 0.f, 0.f, 0.f);
    #pragma unroll
    for (int kp = 0; kp < LW; ++kp) {
      int ck = cs[kp];
      if (ck != 0) {
        float wv = w[hh * LW + kp];
        float4 ev = EV4[ck * (DIM / 4) + t];
        acc.x += wv * ev.x; acc.y += wv * ev.y;
        acc.z += wv * ev.z; acc.w += wv * ev.w;
      }
    }
    acc.x *= invc; acc.y *= invc; acc.z *= invc; acc.w *= invc;
    ((float4*)word_pooled)[(size_t)n * (DIM / 4) + t] = acc;
  }
}

// ---------------- exclusive scan of n_words (2048 = 256*8) ----------------
__global__ __launch_bounds__(256) void k_scan(const int* __restrict__ nw, int* __restrict__ offs) {
  __shared__ int part[256];
  const int t = threadIdx.x;
  int v[8];
  int s = 0;
  #pragma unroll
  for (int i = 0; i < 8; ++i) { v[i] = nw[t * 8 + i]; s += v[i]; }
  part[t] = s;
  __syncthreads();
  if (t == 0) {
    int a = 0;
    for (int i = 0; i < 256; ++i) { int x = part[i]; part[i] = a; a += x; }
    offs[GNAMES] = a;
  }
  __syncthreads();
  int a = part[t];
  #pragma unroll
  for (int i = 0; i < 8; ++i) { offs[t * 8 + i] = a; a += v[i]; }
}

// ---------------- name-level mean over word groups ----------------
__global__ __launch_bounds__(256) void k_name_pool(const float* __restrict__ wp,
                                                   const int* __restrict__ offs,
                                                   float* __restrict__ np_) {
  const int idx = blockIdx.x * 256 + threadIdx.x;  // < GNAMES*DIM
  const int g = idx >> 9, d = idx & 511;
  const int o0 = offs[g], o1 = offs[g + 1];
  float acc = 0.f;
  for (int wi = o0; wi < o1; ++wi) acc += wp[(size_t)wi * DIM + d];
  np_[idx] = (o1 > o0) ? acc / (float)(o1 - o0) : 0.f;
}

extern "C" void kernel_launch(void* const* d_in, const int* in_sizes, int n_in,
                              void* d_out, int out_size, void* d_ws, size_t ws_size,
                              hipStream_t stream) {
  const int*   inputs  = (const int*)d_in[0];
  const int*   n_words = (const int*)d_in[1];
  const float* emb     = (const float*)d_in[3];
  const float* Wq      = (const float*)d_in[4];
  const float* Wk      = (const float*)d_in[5];
  const float* Wv      = (const float*)d_in[6];
  const float* Wo      = (const float*)d_in[7];
  const float* W1      = (const float*)d_in[8];
  const float* W2      = (const float*)d_in[9];
  float* out = (float*)d_out;

  // workspace layout (floats)
  float* ws  = (float*)d_ws;
  float* EQ  = ws;                   // 128*512      = 65536
  float* EK  = ws + 65536;           // 128*512
  float* EV  = ws + 131072;          // 128*512
  float* TAB = ws + 196608;          // 128*128*8    = 131072 (exp table, [c1][c2][h])
  float* WF  = ws + 327680;          // 512*512      = 262144
  float* WP  = ws + 589824;          // 8192*512     = 4194304
  float* NP  = ws + 4784128;         // 2048*512     = 1048576
  float* H1  = ws + 5832704;         // 2048*512     = 1048576
  int*   OFFS = (int*)(ws + 6881280); // 2049 ints   (total ~26.3 MiB)

  // EQ/EK/EV = emb @ W{q,k,v}   (M=128, N=512, K=512)
  k_sgemm<0><<<dim3(8, 2), 256, 0, stream>>>(emb, Wq, EQ, 128, 512, 512);
  k_sgemm<0><<<dim3(8, 2), 256, 0, stream>>>(emb, Wk, EK, 128, 512, 512);
  k_sgemm<0><<<dim3(8, 2), 256, 0, stream>>>(emb, Wv, EV, 128, 512, 512);
  // Wfused = Wo @ W1 (512x512x512)
  k_sgemm<0><<<dim3(8, 8), 256, 0, stream>>>(Wo, W1, WF, 512, 512, 512);
  // exp(qk) score table
  k_qk_tab<<<dim3(VOC, NH), 128, 0, stream>>>(EQ, EK, TAB);
  // word-group offsets
  k_scan<<<1, 256, 0, stream>>>(n_words, OFFS);
  // attention + char-mean pooling per word
  k_attn<<<NWORDS, 192, 0, stream>>>(inputs, TAB, EV, WP);
  // name-level mean pooling
  k_name_pool<<<(GNAMES * DIM) / 256, 256, 0, stream>>>(WP, OFFS, NP);
  // h1 = tanh(NP @ WF)   (2048x512x512)
  k_sgemm<1><<<dim3(8, 32), 256, 0, stream>>>(NP, WF, H1, 2048, 512, 512);
  // out = tanh(h1 @ W2)  (2048x256x512)
  k_sgemm<1><<<dim3(4, 32), 256, 0, stream>>>(H1, W2, out, 2048, F2, 512);
}

// Round 3
// 121.389 us; speedup vs baseline: 3.8691x; 1.9633x over previous
//
#include <hip/hip_runtime.h>
#include <math.h>

// Problem constants (fixed by setup_inputs)
#define NWORDS 8192
#define LW     24
#define VOC    128
#define DIM    512
#define NH     8
#define DKH    64
#define GNAMES 2048
#define F2     256

// stage-1 fused output layout (floats): [EQ 65536 | EK 65536 | EV 65536 | WF 262144]
#define S1_LEN 458752

// =================== double-buffered 64x64 fp32 GEMM body ====================
// 256 threads, BK=16, 4x4 register tile, one barrier per K-step.
#define GEMM_BODY(A_, B_, K_, N_, m0_, n0_, kbeg_, kchunk_)                         \
  __shared__ float As[2][16][68];                                                   \
  __shared__ float Bs[2][16][68];                                                   \
  const int t = threadIdx.x, tx = t & 15, ty = t >> 4;                              \
  float acc[4][4] = {};                                                             \
  float ra[4], rb[4];                                                               \
  _Pragma("unroll")                                                                 \
  for (int i = 0; i < 4; ++i) { int idx = t + 256 * i;                              \
    ra[i] = A_[(size_t)(m0_ + (idx >> 4)) * K_ + kbeg_ + (idx & 15)]; }             \
  _Pragma("unroll")                                                                 \
  for (int i = 0; i < 4; ++i) { int idx = t + 256 * i;                              \
    rb[i] = B_[(size_t)(kbeg_ + (idx >> 6)) * N_ + n0_ + (idx & 63)]; }             \
  _Pragma("unroll")                                                                 \
  for (int i = 0; i < 4; ++i) { int idx = t + 256 * i; As[0][idx & 15][idx >> 4] = ra[i]; } \
  _Pragma("unroll")                                                                 \
  for (int i = 0; i < 4; ++i) { int idx = t + 256 * i; Bs[0][idx >> 6][idx & 63] = rb[i]; } \
  __syncthreads();                                                                  \
  int buf = 0;                                                                      \
  for (int k0 = kbeg_; k0 < kbeg_ + kchunk_; k0 += 16) {                            \
    const bool more = (k0 + 16 < kbeg_ + kchunk_);                                  \
    if (more) {                                                                     \
      _Pragma("unroll")                                                             \
      for (int i = 0; i < 4; ++i) { int idx = t + 256 * i;                          \
        ra[i] = A_[(size_t)(m0_ + (idx >> 4)) * K_ + (k0 + 16) + (idx & 15)]; }     \
      _Pragma("unroll")                                                             \
      for (int i = 0; i < 4; ++i) { int idx = t + 256 * i;                          \
        rb[i] = B_[(size_t)(k0 + 16 + (idx >> 6)) * N_ + n0_ + (idx & 63)]; }       \
    }                                                                               \
    _Pragma("unroll")                                                               \
    for (int k = 0; k < 16; ++k) {                                                  \
      float a[4], b[4];                                                             \
      _Pragma("unroll")                                                             \
      for (int i = 0; i < 4; ++i) a[i] = As[buf][k][ty * 4 + i];                    \
      _Pragma("unroll")                                                             \
      for (int j = 0; j < 4; ++j) b[j] = Bs[buf][k][tx * 4 + j];                    \
      _Pragma("unroll")                                                             \
      for (int i = 0; i < 4; ++i)                                                   \
        _Pragma("unroll")                                                           \
        for (int j = 0; j < 4; ++j) acc[i][j] += a[i] * b[j];                       \
    }                                                                               \
    if (more) {                                                                     \
      _Pragma("unroll")                                                             \
      for (int i = 0; i < 4; ++i) { int idx = t + 256 * i; As[buf ^ 1][idx & 15][idx >> 4] = ra[i]; } \
      _Pragma("unroll")                                                             \
      for (int i = 0; i < 4; ++i) { int idx = t + 256 * i; Bs[buf ^ 1][idx >> 6][idx & 63] = rb[i]; } \
      __syncthreads();                                                              \
      buf ^= 1;                                                                     \
    }                                                                               \
  }

// ---- stage-1 fused GEMM: EQ/EK/EV (128x512) + WF=Wo@W1 (512x512), all K=512 ----
// grid (112 tiles, NSPLIT), writes partials P[s][S1_LEN]
template<int NSPLIT>
__global__ __launch_bounds__(256) void k_stage1(const float* __restrict__ emb,
                                                const float* __restrict__ Wq,
                                                const float* __restrict__ Wk,
                                                const float* __restrict__ Wv,
                                                const float* __restrict__ Wo,
                                                const float* __restrict__ W1,
                                                float* __restrict__ P) {
  const int tid = blockIdx.x, s = blockIdx.y;
  const float *A, *B;
  int coff, m0, n0;
  if (tid < 48) {
    const int g = tid >> 4, mt = tid & 15;
    A = emb;
    B = (g == 0) ? Wq : ((g == 1) ? Wk : Wv);
    coff = g * 65536;
    m0 = (mt >> 3) * 64; n0 = (mt & 7) * 64;
  } else {
    const int id = tid - 48;
    A = Wo; B = W1; coff = 3 * 65536;
    m0 = (id >> 3) * 64; n0 = (id & 7) * 64;
  }
  const int kchunk = 512 / NSPLIT, kbeg = s * kchunk;
  GEMM_BODY(A, B, 512, 512, m0, n0, kbeg, kchunk)
  float* Cp = P + (size_t)s * S1_LEN + coff;
  #pragma unroll
  for (int i = 0; i < 4; ++i) {
    float4 v = make_float4(acc[i][0], acc[i][1], acc[i][2], acc[i][3]);
    *(float4*)&Cp[(size_t)(m0 + ty * 4 + i) * 512 + n0 + tx * 4] = v;
  }
}

// ---- generic GEMM: C = act(A@B) (split over gridDim.z into partials) ----
template<int ACT>
__global__ __launch_bounds__(256) void k_gemm64(const float* __restrict__ A,
                                                const float* __restrict__ B,
                                                float* __restrict__ C,
                                                int M, int N, int K, int kchunk) {
  const int m0 = blockIdx.y * 64, n0 = blockIdx.x * 64;
  const int kbeg = blockIdx.z * kchunk;
  GEMM_BODY(A, B, K, N, m0, n0, kbeg, kchunk)
  float* Cp = C + (size_t)blockIdx.z * M * N;
  #pragma unroll
  for (int i = 0; i < 4; ++i) {
    float4 v = make_float4(acc[i][0], acc[i][1], acc[i][2], acc[i][3]);
    if (ACT) { v.x = tanhf(v.x); v.y = tanhf(v.y); v.z = tanhf(v.z); v.w = tanhf(v.w); }
    *(float4*)&Cp[(size_t)(m0 + ty * 4 + i) * N + n0 + tx * 4] = v;
  }
}

// ---- sum S partial buffers (stride floats apart), optional tanh ----
template<int ACT, int S>
__global__ __launch_bounds__(256) void k_reduce(const float* __restrict__ P,
                                                float* __restrict__ O,
                                                int len4, int stride4) {
  const int i = blockIdx.x * 256 + threadIdx.x;
  if (i >= len4) return;
  const float4* P4 = (const float4*)P;
  float4 a = P4[i];
  #pragma unroll
  for (int s = 1; s < S; ++s) {
    float4 b = P4[(size_t)s * stride4 + i];
    a.x += b.x; a.y += b.y; a.z += b.z; a.w += b.w;
  }
  if (ACT) { a.x = tanhf(a.x); a.y = tanhf(a.y); a.z = tanhf(a.z); a.w = tanhf(a.w); }
  ((float4*)O)[i] = a;
}

// ---- exp(qk) table: ETAB[c1][c2][h] = exp((EQ[c1,h*64:] . EK[c2,h*64:]) / 8) ----
__global__ __launch_bounds__(128) void k_qk_tab(const float* __restrict__ EQ,
                                                const float* __restrict__ EK,
                                                float* __restrict__ etab) {
  const int c1 = blockIdx.x, h = blockIdx.y, c2 = threadIdx.x;
  __shared__ float qrow[DKH];
  if (threadIdx.x < DKH) qrow[threadIdx.x] = EQ[c1 * DIM + h * DKH + threadIdx.x];
  __syncthreads();
  const float* krow = EK + c2 * DIM + h * DKH;
  float acc = 0.f;
  #pragma unroll
  for (int d = 0; d < DKH; ++d) acc += qrow[d] * krow[d];
  etab[((size_t)c1 * VOC + c2) * NH + h] = __expf(acc * 0.125f);
}

// ---- exclusive scan of n_words (2048 = 256*8) ----
__global__ __launch_bounds__(256) void k_scan(const int* __restrict__ nw, int* __restrict__ offs) {
  __shared__ int part[256];
  const int t = threadIdx.x;
  int v[8]; int s = 0;
  #pragma unroll
  for (int i = 0; i < 8; ++i) { v[i] = nw[t * 8 + i]; s += v[i]; }
  part[t] = s;
  __syncthreads();
  if (t == 0) {
    int a = 0;
    for (int i = 0; i < 256; ++i) { int x = part[i]; part[i] = a; a += x; }
    offs[GNAMES] = a;
  }
  __syncthreads();
  int a = part[t];
  #pragma unroll
  for (int i = 0; i < 8; ++i) { offs[t * 8 + i] = a; a += v[i]; }
}

// ---- fused attention + char-mean + name-mean: one block per NAME ----
// 192 threads = 24 q-positions x 8 heads (t = q*8 + h, h fastest -> 32B gathers).
// In-register softmax row; q-reduction via shfl_xor (lane = (q%8)*8+h).
__global__ __launch_bounds__(192) void k_attn(const int* __restrict__ inputs,
                                              const int* __restrict__ offs,
                                              const float* __restrict__ etab,
                                              const float* __restrict__ EV,
                                              float* __restrict__ NP) {
  const int g = blockIdx.x, t = threadIdx.x;
  const int o0 = offs[g], o1 = offs[g + 1];
  __shared__ int   cs[LW];
  __shared__ float wpart[3][NH][25];  // per-wave q-partials, pad 25 vs conflicts
  const int q = t >> 3, h = t & 7;
  const int wv = t >> 6, lane = t & 63;
  float4 acc = make_float4(0.f, 0.f, 0.f, 0.f);

  for (int wi = o0; wi < o1; ++wi) {
    __syncthreads();  // previous word's phase-3 reads done before cs/wpart reuse
    if (t < LW) cs[t] = inputs[(size_t)wi * LW + t];
    __syncthreads();

    // per-(q,h) normalized attention row in registers
    const int cq = cs[q];
    float row[LW];
    float inv = 0.f;
    if (cq != 0) {
      const float* tb = etab + (size_t)cq * (VOC * NH) + h;
      float sum = 0.f;
      #pragma unroll
      for (int kp = 0; kp < LW; ++kp) {
        int ck = cs[kp];
        float e = (ck != 0) ? tb[(size_t)ck * NH] : 0.f;
        row[kp] = e; sum += e;
      }
      inv = 1.f / sum;
    } else {
      #pragma unroll
      for (int kp = 0; kp < LW; ++kp) row[kp] = 0.f;
    }
    // reduce over q within wave (bits 3/4/5 of lane), 3 waves -> 3 partials
    #pragma unroll
    for (int kp = 0; kp < LW; ++kp) {
      float v = row[kp] * inv;
      v += __shfl_xor(v, 8, 64);
      v += __shfl_xor(v, 16, 64);
      v += __shfl_xor(v, 32, 64);
      if (lane < 8) wpart[wv][lane][kp] = v;
    }
    int cnt = 0;
    #pragma unroll
    for (int l = 0; l < LW; ++l) cnt += (cs[l] != 0);
    __syncthreads();

    // pooled accumulate: acc += (1/cnt) * sum_kp w[h][kp] * EV[ck][j]
    if (t < 128) {
      const float invc = cnt ? 1.f / (float)cnt : 0.f;
      const int hh = t >> 4;
      const float4* EV4 = (const float4*)EV;
      float4 a2 = make_float4(0.f, 0.f, 0.f, 0.f);
      #pragma unroll
      for (int kp = 0; kp < LW; ++kp) {
        int ck = cs[kp];
        if (ck != 0) {
          float w = wpart[0][hh][kp] + wpart[1][hh][kp] + wpart[2][hh][kp];
          float4 ev = EV4[(size_t)ck * (DIM / 4) + t];
          a2.x += w * ev.x; a2.y += w * ev.y; a2.z += w * ev.z; a2.w += w * ev.w;
        }
      }
      acc.x += invc * a2.x; acc.y += invc * a2.y;
      acc.z += invc * a2.z; acc.w += invc * a2.w;
    }
  }
  if (t < 128) {
    const float invn = (o1 > o0) ? 1.f / (float)(o1 - o0) : 0.f;
    acc.x *= invn; acc.y *= invn; acc.z *= invn; acc.w *= invn;
    ((float4*)NP)[(size_t)g * (DIM / 4) + t] = acc;
  }
}

extern "C" void kernel_launch(void* const* d_in, const int* in_sizes, int n_in,
                              void* d_out, int out_size, void* d_ws, size_t ws_size,
                              hipStream_t stream) {
  const int*   inputs  = (const int*)d_in[0];
  const int*   n_words = (const int*)d_in[1];
  const float* emb     = (const float*)d_in[3];
  const float* Wq      = (const float*)d_in[4];
  const float* Wk      = (const float*)d_in[5];
  const float* Wv      = (const float*)d_in[6];
  const float* Wo      = (const float*)d_in[7];
  const float* W1      = (const float*)d_in[8];
  const float* W2      = (const float*)d_in[9];
  float* out = (float*)d_out;

  // workspace layout (floats), ~15 MB total
  float* ws  = (float*)d_ws;
  float* ES  = ws;                      // 458752: [EQ|EK|EV|WF]
  float* BIG = ws + 458752;             // 1048576: split-K partials (reused)
  float* TAB = ws + 1507328;            // 131072: exp table [c1][c2][h]
  float* NP  = ws + 1638400;            // 2048*512
  float* H1  = ws + 2686976;            // 2048*512
  int*  OFFS = (int*)(ws + 3735552);    // 2049 ints

  k_scan<<<1, 256, 0, stream>>>(n_words, OFFS);
  // stage-1 fused GEMMs, split-K=2 -> 224 blocks
  k_stage1<2><<<dim3(112, 2), 256, 0, stream>>>(emb, Wq, Wk, Wv, Wo, W1, BIG);
  k_reduce<0, 2><<<S1_LEN / 4 / 256, 256, 0, stream>>>(BIG, ES, S1_LEN / 4, S1_LEN / 4);
  // exp(qk) table from EQ, EK
  k_qk_tab<<<dim3(VOC, NH), 128, 0, stream>>>(ES, ES + 65536, TAB);
  // attention + char-mean + name-mean (one block per name)
  k_attn<<<GNAMES, 192, 0, stream>>>(inputs, OFFS, TAB, ES + 131072, NP);
  // h1 = tanh(NP @ WF)  (2048x512x512, tanh inline)
  k_gemm64<1><<<dim3(8, 32, 1), 256, 0, stream>>>(NP, ES + 196608, H1, 2048, 512, 512, 512);
  // out = tanh(H1 @ W2) (2048x256x512), split-K=2 + tanh in reduce
  k_gemm64<0><<<dim3(4, 32, 2), 256, 0, stream>>>(H1, W2, BIG, 2048, F2, 512, 256);
  k_reduce<1, 2><<<(GNAMES * F2) / 4 / 256, 256, 0, stream>>>(BIG, out, (GNAMES * F2) / 4, (GNAMES * F2) / 4);
}